// Round 15
// baseline (2723.625 us; speedup 1.0000x reference)
//
#include <hip/hip_runtime.h>
#include <float.h>
#include <math.h>

// Net_69664369541652: 8-iteration matching pursuit.
// One block per (b,t) position (2048 blocks, 512 threads).
// Round 15: B-stationary MFMA conv. Round-14 counters: MFMA-busy 310us
// (= flop floor), but B-fragments (m-invariant) were reloaded per m-tile
// -> 32 GB L2 (~0.93 ms), occupancy 24% (1 blk/CU, 40-reg A-hoist), and
// ct{t{3 dep MFMAs}} had no ILP. New nest: ct{ t{ B once; m{ A; mfma x3 }}}
// -> B traffic /6 (5.4 GB), 6 independent acc chains. A-frags now read as
// single aligned ds_read_b128 from 8 offset-replicated bf16 LDS copies
// (yA[r][i] = yap[i+r]; 8q+r=P identity). eparts accumulate across ct in
// LDS (same order -> bit-identical energies; r14 absmax was 0.0).

#define NITER 8

typedef float f32x4 __attribute__((ext_vector_type(4)));
typedef short s16x8 __attribute__((ext_vector_type(8)));

union U16B { uint4 u4; unsigned int u[4]; s16x8 v; };

__device__ __forceinline__ unsigned short f2bf(float f) {
    unsigned int u = __float_as_uint(f);
    unsigned int r = (u + 0x7FFFu + ((u >> 16) & 1u)) >> 16;   // RNE
    return (unsigned short)r;
}
__device__ __forceinline__ float bf2f(unsigned short h) {
    return __uint_as_float(((unsigned int)h) << 16);
}

__device__ __forceinline__ void argmaxStep(float &v, int &i, float v2, int i2) {
    if (v2 > v || (v2 == v && i2 < i)) { v = v2; i = i2; }
}

// Prep: encw (w-major f32 [160][512]) -> whi/wlo (bf16 hi/lo, c-major [512][160])
__global__ void prep_kernel(const float* __restrict__ encw,
                            unsigned short* __restrict__ whi,
                            unsigned short* __restrict__ wlo)
{
    int o = blockIdx.x * 256 + threadIdx.x;      // 81920 total
    if (o >= 512 * 160) return;
    int c = o / 160, w = o % 160;
    float f = encw[w * 512 + c];
    unsigned short h = f2bf(f);
    unsigned short l = f2bf(f - bf2f(h));
    whi[o] = h;
    wlo[o] = l;
}

__global__ __launch_bounds__(512, 2)
void mp_kernel(const float* __restrict__ x, const float* __restrict__ y,
               const float* __restrict__ encw, const float* __restrict__ encb,
               const float* __restrict__ decw, const float* __restrict__ decb,
               const unsigned short* __restrict__ whi,
               const unsigned short* __restrict__ wlo,
               double* __restrict__ lossSum, int* __restrict__ nzCount)
{
    const int tid  = threadIdx.x;
    const int bt   = blockIdx.x;
    const int lane = tid & 63;
    const int wid  = tid >> 6;
    const int c    = tid;            // encoder channel owned by this thread
    const int lg   = lane >> 4;      // k-block / D-row group
    const int li   = lane & 15;      // A-row (s) / B-col (c) within tile

    __shared__ __align__(16) float yap[256];   // zero-padded y_align_attn (fp32)
    // 8 offset-replicated bf16 copies: yA[r] shorts[i] = bf16(yap[i+r]) (hi),
    // yA[8+r] = lo part. 136 dwords (272 shorts) per array, 16B-aligned rows.
    __shared__ __align__(16) unsigned int yA[16][136];
    __shared__ float xr[80], yr[80], yy[80];
    __shared__ __align__(16) float hrow[512];
    __shared__ float xext[160];
    __shared__ float eparts[96 * 8];           // energy partials [s][wave]
    __shared__ float selVal[64];
    __shared__ int   selIdx[64];
    __shared__ float rv[8];
    __shared__ int   ri[8];
    __shared__ int   cnt;
    __shared__ int   theta_s, hind_s;
    __shared__ float ysq_s, bf1, bf2;

    float myy = 0.f;
    if (tid < 80) {
        xr[tid] = x[bt * 80 + tid];
        myy = y[bt * 80 + tid];
        yr[tid] = myy;
        yy[tid] = myy;
    }
    if (tid < 256) yap[tid] = 0.f;
    for (int k = tid; k < 16 * 136; k += 512) ((unsigned int*)yA)[k] = 0u;

    // global nonzero count of y (denominator of seq_loss), once
    {
        unsigned long long b = __ballot(tid < 80 && myy != 0.0f);
        if (lane == 0 && wid < 2) {
            int n = (int)__popcll(b);
            if (n) atomicAdd(nzCount, n);
        }
    }

    const float bc = encb[c];                  // for fp32 h-recompute
    float bcv[4];                              // bias for MFMA energy cols
    #pragma unroll
    for (int ct = 0; ct < 4; ++ct) bcv[ct] = encb[((wid * 4 + ct) << 4) + li];

    bool   mprev = false;
    double blockLoss = 0.0;

    for (int iter = 0; iter < NITER; ++iter) {
        __syncthreads();

        // ---------- ||y_res||^2 ----------
        {
            float v = 0.f;
            if (tid < 80) { float t = yr[tid]; v = t * t; }
            #pragma unroll
            for (int off = 32; off; off >>= 1) v += __shfl_xor(v, off);
            if (lane == 0) rv[wid] = v;
            __syncthreads();
            if (tid == 0) {
                float s = 0.f;
                for (int k = 0; k < 8; ++k) s += rv[k];
                ysq_s = s;
            }
            __syncthreads();
        }

        // ---------- selector: cosine sim over 159 shifts, argmax ----------
        {
            float sv = -FLT_MAX; int si = 0x7fffffff;
            if (tid < 159) {
                int s = tid;
                int jlo = (s - 79 > 0) ? s - 79 : 0;
                int jhi = (s + 1 < 80) ? s + 1 : 80;
                float num = 0.f, wn = 0.f;
                for (int j = jlo; j < jhi; ++j) {
                    float xv = xr[j];
                    num += xv * yr[j + 79 - s];
                    wn  += xv * xv;
                }
                float den = sqrtf(ysq_s) * sqrtf(wn);
                sv = (den == 0.f) ? 0.f : num / den;
                si = s;
            }
            #pragma unroll
            for (int off = 32; off; off >>= 1) {
                float v2 = __shfl_xor(sv, off);
                int   i2 = __shfl_xor(si, off);
                argmaxStep(sv, si, v2, i2);
            }
            if (lane == 0) { rv[wid] = sv; ri[wid] = si; }
            __syncthreads();
            if (tid == 0) {
                float bv = rv[0]; int bi = ri[0];
                for (int k = 1; k < 8; ++k) argmaxStep(bv, bi, rv[k], ri[k]);
                theta_s = bi;
            }
            __syncthreads();
        }
        const int theta = theta_s;

        // ---------- softmax attention -> y_align_attn into yap[80..160) ------
        float yao = 0.f, z = -FLT_MAX;
        if (tid < 80) {
            int j = theta + tid - 79;
            if (j >= 0 && j < 80) yao = xr[j];
            z = yao * yy[tid];
        }
        {
            float zm = z;
            #pragma unroll
            for (int off = 32; off; off >>= 1) zm = fmaxf(zm, __shfl_xor(zm, off));
            if (lane == 0) rv[wid] = zm;
            __syncthreads();
            if (tid == 0) {
                float m = rv[0];
                for (int k = 1; k < 8; ++k) m = fmaxf(m, rv[k]);
                bf1 = m;
            }
            __syncthreads();
        }
        float ez = 0.f;
        if (tid < 80) ez = expf(z - bf1);
        {
            float es = ez;
            #pragma unroll
            for (int off = 32; off; off >>= 1) es += __shfl_xor(es, off);
            if (lane == 0) rv[wid] = es;
            __syncthreads();
            if (tid == 0) {
                float s = 0.f;
                for (int k = 0; k < 8; ++k) s += rv[k];
                bf2 = s;
            }
            __syncthreads();
        }
        if (tid < 80) yap[80 + tid] = yao * (ez / bf2);
        __syncthreads();

        // ---------- rebuild 8-offset bf16 hi/lo replicas + zero eparts -------
        if (tid >= 80 && tid < 160) {
            float f0 = yap[tid];
            unsigned short h0 = f2bf(f0);
            unsigned short l0 = f2bf(f0 - bf2f(h0));
            #pragma unroll
            for (int r = 0; r < 8; ++r) {
                ((unsigned short*)yA[r])[tid - r]     = h0;
                ((unsigned short*)yA[8 + r])[tid - r] = l0;
            }
        }
        eparts[tid] = 0.f;
        if (tid < 256) eparts[512 + tid] = 0.f;
        __syncthreads();

        // ---------- encoder conv via MFMA (bf16x3), B-stationary -------------
        // H = Y*W: A[s,k]=yap[k+s] (M=96, 6 m-tiles), B[k,c] (wave owns 4
        // c-tiles), K=160 in 5 t-steps. For each (ct,t): load B once, sweep
        // 6 m-tiles (A = 1 ds_read_b128 each from replica r=li&7).
        {
            const int r = li & 7;
            const unsigned int* aH = yA[r];
            const unsigned int* aL = yA[8 + r];
            const int qb = lg + (li >> 3);

            for (int ct = 0; ct < 4; ++ct) {
                const unsigned short* wh = whi + (((wid * 4 + ct) << 4) + li) * 160;
                const unsigned short* wl = wlo + (((wid * 4 + ct) << 4) + li) * 160;
                f32x4 acc[6];
                #pragma unroll
                for (int m = 0; m < 6; ++m) acc[m] = (f32x4){0.f, 0.f, 0.f, 0.f};

                #pragma unroll
                for (int t = 0; t < 5; ++t) {
                    U16B bh, bl;
                    bh.u4 = *(const uint4*)(wh + (t << 5) + (lg << 3));
                    bl.u4 = *(const uint4*)(wl + (t << 5) + (lg << 3));
                    #pragma unroll
                    for (int m = 0; m < 6; ++m) {
                        const int q4 = (qb + 2 * m + 4 * t) << 2;
                        U16B ah, al;
                        ah.u4 = *(const uint4*)(aH + q4);
                        al.u4 = *(const uint4*)(aL + q4);
                        acc[m] = __builtin_amdgcn_mfma_f32_16x16x32_bf16(ah.v, bh.v, acc[m], 0, 0, 0);
                        acc[m] = __builtin_amdgcn_mfma_f32_16x16x32_bf16(ah.v, bl.v, acc[m], 0, 0, 0);
                        acc[m] = __builtin_amdgcn_mfma_f32_16x16x32_bf16(al.v, bh.v, acc[m], 0, 0, 0);
                    }
                }

                const float b0 = bcv[ct];
                #pragma unroll
                for (int m = 0; m < 6; ++m) {
                    float e0 = acc[m][0] + b0; e0 *= e0;
                    float e1 = acc[m][1] + b0; e1 *= e1;
                    float e2 = acc[m][2] + b0; e2 *= e2;
                    float e3 = acc[m][3] + b0; e3 *= e3;
                    #pragma unroll
                    for (int off = 1; off < 16; off <<= 1) {
                        e0 += __shfl_xor(e0, off);
                        e1 += __shfl_xor(e1, off);
                        e2 += __shfl_xor(e2, off);
                        e3 += __shfl_xor(e3, off);
                    }
                    if (li == 0) {
                        const int s = m * 16 + lg * 4;
                        eparts[(s + 0) * 8 + wid] += e0;
                        eparts[(s + 1) * 8 + wid] += e1;
                        eparts[(s + 2) * 8 + wid] += e2;
                        eparts[(s + 3) * 8 + wid] += e3;
                    }
                }
            }
        }
        __syncthreads();

        // ---------- energy pooling argmax over 81 shifts ----------
        {
            float ev = -FLT_MAX; int ei = 0x7fffffff;
            if (tid < 81) {
                float e = 0.f;
                #pragma unroll
                for (int k = 0; k < 8; ++k) e += eparts[tid * 8 + k];
                ev = e; ei = tid;
            }
            #pragma unroll
            for (int off = 32; off; off >>= 1) {
                float v2 = __shfl_xor(ev, off);
                int   i2 = __shfl_xor(ei, off);
                argmaxStep(ev, ei, v2, i2);
            }
            if (lane == 0) { rv[wid] = ev; ri[wid] = ei; }
            __syncthreads();
            if (tid == 0) {
                float bv = rv[0]; int bi = ri[0];
                for (int k = 1; k < 8; ++k) argmaxStep(bv, bi, rv[k], ri[k]);
                hind_s = bi;
            }
            __syncthreads();
        }
        const int hind = hind_s;

        // ---------- recompute h[hind, c] in exact fp32 (80 FMAs) ----------
        float hv = bc;
        {
            const float* wp = encw + c;
            #pragma unroll 4
            for (int v = 80 - hind; v < 160 - hind; ++v)
                hv += wp[v * 512] * yap[v + hind];
        }
        if (iter > 0 && mprev) hv = 0.f;
        hrow[c] = hv;
        if (tid == 0) cnt = 0;
        __syncthreads();

        // ---------- exact top-64 by rank count ----------
        {
            const float k0 = hv * hv;
            int rank = 0;
            const float4* h4 = (const float4*)hrow;
            for (int q = 0; q < 128; ++q) {
                float4 hq = h4[q];
                int cb = q * 4;
                float ka = hq.x * hq.x, kb = hq.y * hq.y;
                float kc = hq.z * hq.z, kd = hq.w * hq.w;
                rank += (ka > k0) || (ka == k0 && (cb + 0) < c);
                rank += (kb > k0) || (kb == k0 && (cb + 1) < c);
                rank += (kc > k0) || (kc == k0 && (cb + 2) < c);
                rank += (kd > k0) || (kd == k0 && (cb + 3) < c);
            }
            bool sel = rank < 64;
            mprev = mprev || sel;
            if (sel) {
                int p = atomicAdd(&cnt, 1);
                selIdx[p] = c;
                selVal[p] = hv;
            }
        }
        __syncthreads();

        // ---------- sparse decoder: x_ext = h_sel @ dec_w + dec_b ----------
        if (tid < 160) {
            float a2 = decb[tid];
            for (int k = 0; k < 64; ++k)
                a2 += selVal[k] * decw[selIdx[k] * 160 + tid];
            xext[tid] = a2;
        }
        __syncthreads();

        // ---------- y_ele gather, loss, residual updates ----------
        float ye = 0.f, yrv = 0.f, lp = 0.f;
        if (tid < 80) {
            ye  = xext[80 - hind + tid];
            yrv = yr[tid];
            float d = ye - yrv;
            lp = (yy[tid] == 0.0f) ? 0.f : d * d;
        }
        {
            float ls = lp;
            #pragma unroll
            for (int off = 32; off; off >>= 1) ls += __shfl_xor(ls, off);
            if (lane == 0) rv[wid] = ls;
            __syncthreads();
            if (tid == 0) {
                float s = 0.f;
                for (int k = 0; k < 8; ++k) s += rv[k];
                blockLoss += (double)s;
            }
        }
        float xe = 0.f;
        if (tid < 80) xe = yap[tid + 159 - theta];
        __syncthreads();
        if (tid < 80) {
            yr[tid] = yrv - ye;
            xr[tid] -= xe;
        }
    }

    if (tid == 0) atomicAdd(lossSum, blockLoss);
}

__global__ void finish_kernel(const double* __restrict__ lossSum,
                              const int* __restrict__ nz,
                              float* __restrict__ out)
{
    int n = *nz;
    if (n < 1) n = 1;
    out[0] = (float)(*lossSum / (8.0 * (double)n));
}

extern "C" void kernel_launch(void* const* d_in, const int* in_sizes, int n_in,
                              void* d_out, int out_size, void* d_ws, size_t ws_size,
                              hipStream_t stream) {
    (void)in_sizes; (void)n_in; (void)out_size; (void)ws_size;
    const float* x    = (const float*)d_in[0];
    const float* y    = (const float*)d_in[1];
    const float* encw = (const float*)d_in[2];
    const float* encb = (const float*)d_in[3];
    const float* decw = (const float*)d_in[4];
    const float* decb = (const float*)d_in[5];

    unsigned short* whi = (unsigned short*)d_ws;                       // 512*160 bf16
    unsigned short* wlo = (unsigned short*)((char*)d_ws + 163840);     // 512*160 bf16
    double* lossSum = (double*)((char*)d_ws + 327680);
    int*    nz      = (int*)((char*)d_ws + 327688);

    hipMemsetAsync((char*)d_ws + 327680, 0, 16, stream);
    prep_kernel<<<320, 256, 0, stream>>>(encw, whi, wlo);
    mp_kernel<<<2048, 512, 0, stream>>>(x, y, encw, encb, decw, decb,
                                        whi, wlo, lossSum, nz);
    finish_kernel<<<1, 1, 0, stream>>>(lossSum, nz, (float*)d_out);
}

// Round 16
// 2010.889 us; speedup vs baseline: 1.3544x; 1.3544x over previous
//
#include <hip/hip_runtime.h>
#include <float.h>
#include <math.h>

// Net_69664369541652: 8-iteration matching pursuit.
// Round 16: 256-thread blocks, 2 channels/thread (was 512x1). r15 counters
// showed conv operand traffic was NOT the limiter (B /6 -> no change);
// wall = 953us VALU + 310us MFMA + ~1800us EXPOSED LATENCY with 1 block/CU
// (24% occ at >64 regs) -> every barrier stalls the whole CU. 256-thread
// blocks give >=2 independent barrier domains per CU; block A's stalls are
// covered by block B. Same total work: conv = 4 waves x 8 c-tiles (acc[6]
// reused per ct), channel phases handle c=tid and c=tid+256, hrow scan
// shared across both rank keys. Energy partials: 4 wave slots.

#define NITER 8

typedef float f32x4 __attribute__((ext_vector_type(4)));
typedef short s16x8 __attribute__((ext_vector_type(8)));

union U16B { uint4 u4; unsigned int u[4]; s16x8 v; };

__device__ __forceinline__ unsigned short f2bf(float f) {
    unsigned int u = __float_as_uint(f);
    unsigned int r = (u + 0x7FFFu + ((u >> 16) & 1u)) >> 16;   // RNE
    return (unsigned short)r;
}
__device__ __forceinline__ float bf2f(unsigned short h) {
    return __uint_as_float(((unsigned int)h) << 16);
}

__device__ __forceinline__ void argmaxStep(float &v, int &i, float v2, int i2) {
    if (v2 > v || (v2 == v && i2 < i)) { v = v2; i = i2; }
}

// Prep: encw (w-major f32 [160][512]) -> whi/wlo (bf16 hi/lo, c-major [512][160])
__global__ void prep_kernel(const float* __restrict__ encw,
                            unsigned short* __restrict__ whi,
                            unsigned short* __restrict__ wlo)
{
    int o = blockIdx.x * 256 + threadIdx.x;      // 81920 total
    if (o >= 512 * 160) return;
    int c = o / 160, w = o % 160;
    float f = encw[w * 512 + c];
    unsigned short h = f2bf(f);
    unsigned short l = f2bf(f - bf2f(h));
    whi[o] = h;
    wlo[o] = l;
}

__global__ __launch_bounds__(256, 2)
void mp_kernel(const float* __restrict__ x, const float* __restrict__ y,
               const float* __restrict__ encw, const float* __restrict__ encb,
               const float* __restrict__ decw, const float* __restrict__ decb,
               const unsigned short* __restrict__ whi,
               const unsigned short* __restrict__ wlo,
               double* __restrict__ lossSum, int* __restrict__ nzCount)
{
    const int tid  = threadIdx.x;
    const int bt   = blockIdx.x;
    const int lane = tid & 63;
    const int wid  = tid >> 6;       // 0..3
    const int c0   = tid;            // first channel owned by this thread
    const int c1   = tid + 256;      // second channel
    const int lg   = lane >> 4;      // k-block / D-row group
    const int li   = lane & 15;      // A-row (s) / B-col (c) within tile

    __shared__ __align__(16) float yap[256];   // zero-padded y_align_attn (fp32)
    // 8 offset-replicated bf16 copies: yA[r] shorts[i] = bf16(yap[i+r]) (hi),
    // yA[8+r] = lo part. 136 dwords per array, rows 16B-aligned (544B stride).
    __shared__ __align__(16) unsigned int yA[16][136];
    __shared__ float xr[80], yr[80], yy[80];
    __shared__ __align__(16) float hrow[512];
    __shared__ float xext[160];
    __shared__ float eparts[96 * 4];           // energy partials [s][wave 0..3]
    __shared__ float selVal[64];
    __shared__ int   selIdx[64];
    __shared__ float rv[4];
    __shared__ int   ri[4];
    __shared__ int   cnt;
    __shared__ int   theta_s, hind_s;
    __shared__ float ysq_s, bf1, bf2;

    float myy = 0.f;
    if (tid < 80) {
        xr[tid] = x[bt * 80 + tid];
        myy = y[bt * 80 + tid];
        yr[tid] = myy;
        yy[tid] = myy;
    }
    yap[tid] = 0.f;
    for (int k = tid; k < 16 * 136; k += 256) ((unsigned int*)yA)[k] = 0u;

    // global nonzero count of y (denominator of seq_loss), once
    {
        unsigned long long b = __ballot(tid < 80 && myy != 0.0f);
        if (lane == 0 && wid < 2) {
            int n = (int)__popcll(b);
            if (n) atomicAdd(nzCount, n);
        }
    }

    const float bcA = encb[c0];                // for fp32 h-recompute
    const float bcB = encb[c1];
    float bcv[8];                              // bias for MFMA energy cols
    #pragma unroll
    for (int ct = 0; ct < 8; ++ct) bcv[ct] = encb[((wid * 8 + ct) << 4) + li];

    bool   mprevA = false, mprevB = false;
    double blockLoss = 0.0;

    for (int iter = 0; iter < NITER; ++iter) {
        __syncthreads();

        // ---------- ||y_res||^2 ----------
        {
            float v = 0.f;
            if (tid < 80) { float t = yr[tid]; v = t * t; }
            #pragma unroll
            for (int off = 32; off; off >>= 1) v += __shfl_xor(v, off);
            if (lane == 0) rv[wid] = v;
            __syncthreads();
            if (tid == 0) {
                float s = 0.f;
                for (int k = 0; k < 4; ++k) s += rv[k];
                ysq_s = s;
            }
            __syncthreads();
        }

        // ---------- selector: cosine sim over 159 shifts, argmax ----------
        {
            float sv = -FLT_MAX; int si = 0x7fffffff;
            if (tid < 159) {
                int s = tid;
                int jlo = (s - 79 > 0) ? s - 79 : 0;
                int jhi = (s + 1 < 80) ? s + 1 : 80;
                float num = 0.f, wn = 0.f;
                for (int j = jlo; j < jhi; ++j) {
                    float xv = xr[j];
                    num += xv * yr[j + 79 - s];
                    wn  += xv * xv;
                }
                float den = sqrtf(ysq_s) * sqrtf(wn);
                sv = (den == 0.f) ? 0.f : num / den;
                si = s;
            }
            #pragma unroll
            for (int off = 32; off; off >>= 1) {
                float v2 = __shfl_xor(sv, off);
                int   i2 = __shfl_xor(si, off);
                argmaxStep(sv, si, v2, i2);
            }
            if (lane == 0) { rv[wid] = sv; ri[wid] = si; }
            __syncthreads();
            if (tid == 0) {
                float bv = rv[0]; int bi = ri[0];
                for (int k = 1; k < 4; ++k) argmaxStep(bv, bi, rv[k], ri[k]);
                theta_s = bi;
            }
            __syncthreads();
        }
        const int theta = theta_s;

        // ---------- softmax attention -> y_align_attn into yap[80..160) ------
        float yao = 0.f, z = -FLT_MAX;
        if (tid < 80) {
            int j = theta + tid - 79;
            if (j >= 0 && j < 80) yao = xr[j];
            z = yao * yy[tid];
        }
        {
            float zm = z;
            #pragma unroll
            for (int off = 32; off; off >>= 1) zm = fmaxf(zm, __shfl_xor(zm, off));
            if (lane == 0) rv[wid] = zm;
            __syncthreads();
            if (tid == 0) {
                float m = rv[0];
                for (int k = 1; k < 4; ++k) m = fmaxf(m, rv[k]);
                bf1 = m;
            }
            __syncthreads();
        }
        float ez = 0.f;
        if (tid < 80) ez = expf(z - bf1);
        {
            float es = ez;
            #pragma unroll
            for (int off = 32; off; off >>= 1) es += __shfl_xor(es, off);
            if (lane == 0) rv[wid] = es;
            __syncthreads();
            if (tid == 0) {
                float s = 0.f;
                for (int k = 0; k < 4; ++k) s += rv[k];
                bf2 = s;
            }
            __syncthreads();
        }
        if (tid < 80) yap[80 + tid] = yao * (ez / bf2);
        __syncthreads();

        // ---------- rebuild 8-offset bf16 hi/lo replicas + zero eparts -------
        if (tid >= 80 && tid < 160) {
            float f0 = yap[tid];
            unsigned short h0 = f2bf(f0);
            unsigned short l0 = f2bf(f0 - bf2f(h0));
            #pragma unroll
            for (int r = 0; r < 8; ++r) {
                ((unsigned short*)yA[r])[tid - r]     = h0;
                ((unsigned short*)yA[8 + r])[tid - r] = l0;
            }
        }
        eparts[tid] = 0.f;
        if (tid < 128) eparts[256 + tid] = 0.f;
        __syncthreads();

        // ---------- encoder conv via MFMA (bf16x3), B-stationary -------------
        // H = Y*W: A[s,k]=yap[k+s] (M=96, 6 m-tiles), B[k,c]. 4 waves x 8
        // c-tiles (ct sequential, acc[6] reused). K=160 in 5 t-steps.
        {
            const int r = li & 7;
            const unsigned int* aH = yA[r];
            const unsigned int* aL = yA[8 + r];
            const int qb = lg + (li >> 3);

            for (int ct = 0; ct < 8; ++ct) {
                const unsigned short* wh = whi + (((wid * 8 + ct) << 4) + li) * 160;
                const unsigned short* wl = wlo + (((wid * 8 + ct) << 4) + li) * 160;
                f32x4 acc[6];
                #pragma unroll
                for (int m = 0; m < 6; ++m) acc[m] = (f32x4){0.f, 0.f, 0.f, 0.f};

                #pragma unroll
                for (int t = 0; t < 5; ++t) {
                    U16B bh, bl;
                    bh.u4 = *(const uint4*)(wh + (t << 5) + (lg << 3));
                    bl.u4 = *(const uint4*)(wl + (t << 5) + (lg << 3));
                    #pragma unroll
                    for (int m = 0; m < 6; ++m) {
                        const int q4 = (qb + 2 * m + 4 * t) << 2;
                        U16B ah, al;
                        ah.u4 = *(const uint4*)(aH + q4);
                        al.u4 = *(const uint4*)(aL + q4);
                        acc[m] = __builtin_amdgcn_mfma_f32_16x16x32_bf16(ah.v, bh.v, acc[m], 0, 0, 0);
                        acc[m] = __builtin_amdgcn_mfma_f32_16x16x32_bf16(ah.v, bl.v, acc[m], 0, 0, 0);
                        acc[m] = __builtin_amdgcn_mfma_f32_16x16x32_bf16(al.v, bh.v, acc[m], 0, 0, 0);
                    }
                }

                const float b0 = bcv[ct];
                #pragma unroll
                for (int m = 0; m < 6; ++m) {
                    float e0 = acc[m][0] + b0; e0 *= e0;
                    float e1 = acc[m][1] + b0; e1 *= e1;
                    float e2 = acc[m][2] + b0; e2 *= e2;
                    float e3 = acc[m][3] + b0; e3 *= e3;
                    #pragma unroll
                    for (int off = 1; off < 16; off <<= 1) {
                        e0 += __shfl_xor(e0, off);
                        e1 += __shfl_xor(e1, off);
                        e2 += __shfl_xor(e2, off);
                        e3 += __shfl_xor(e3, off);
                    }
                    if (li == 0) {
                        const int s = m * 16 + lg * 4;
                        eparts[(s + 0) * 4 + wid] += e0;
                        eparts[(s + 1) * 4 + wid] += e1;
                        eparts[(s + 2) * 4 + wid] += e2;
                        eparts[(s + 3) * 4 + wid] += e3;
                    }
                }
            }
        }
        __syncthreads();

        // ---------- energy pooling argmax over 81 shifts ----------
        {
            float ev = -FLT_MAX; int ei = 0x7fffffff;
            if (tid < 81) {
                float e = 0.f;
                #pragma unroll
                for (int k = 0; k < 4; ++k) e += eparts[tid * 4 + k];
                ev = e; ei = tid;
            }
            #pragma unroll
            for (int off = 32; off; off >>= 1) {
                float v2 = __shfl_xor(ev, off);
                int   i2 = __shfl_xor(ei, off);
                argmaxStep(ev, ei, v2, i2);
            }
            if (lane == 0) { rv[wid] = ev; ri[wid] = ei; }
            __syncthreads();
            if (tid == 0) {
                float bv = rv[0]; int bi = ri[0];
                for (int k = 1; k < 4; ++k) argmaxStep(bv, bi, rv[k], ri[k]);
                hind_s = bi;
            }
            __syncthreads();
        }
        const int hind = hind_s;

        // ---------- recompute h[hind, c] in exact fp32 (80 FMAs x2) ----------
        float hvA = bcA, hvB = bcB;
        {
            const float* wpA = encw + c0;
            const float* wpB = encw + c1;
            #pragma unroll 4
            for (int v = 80 - hind; v < 160 - hind; ++v) {
                float yv = yap[v + hind];
                hvA += wpA[v * 512] * yv;
                hvB += wpB[v * 512] * yv;
            }
        }
        if (iter > 0 && mprevA) hvA = 0.f;
        if (iter > 0 && mprevB) hvB = 0.f;
        hrow[c0] = hvA;
        hrow[c1] = hvB;
        if (tid == 0) cnt = 0;
        __syncthreads();

        // ---------- exact top-64 by rank count (both channels, shared scan) --
        {
            const float k0A = hvA * hvA;
            const float k0B = hvB * hvB;
            int rankA = 0, rankB = 0;
            const float4* h4 = (const float4*)hrow;
            for (int q = 0; q < 128; ++q) {
                float4 hq = h4[q];
                int cb = q * 4;
                float ka = hq.x * hq.x, kb = hq.y * hq.y;
                float kc = hq.z * hq.z, kd = hq.w * hq.w;
                rankA += (ka > k0A) || (ka == k0A && (cb + 0) < c0);
                rankA += (kb > k0A) || (kb == k0A && (cb + 1) < c0);
                rankA += (kc > k0A) || (kc == k0A && (cb + 2) < c0);
                rankA += (kd > k0A) || (kd == k0A && (cb + 3) < c0);
                rankB += (ka > k0B) || (ka == k0B && (cb + 0) < c1);
                rankB += (kb > k0B) || (kb == k0B && (cb + 1) < c1);
                rankB += (kc > k0B) || (kc == k0B && (cb + 2) < c1);
                rankB += (kd > k0B) || (kd == k0B && (cb + 3) < c1);
            }
            bool selA = rankA < 64;
            bool selB = rankB < 64;
            mprevA = mprevA || selA;
            mprevB = mprevB || selB;
            if (selA) {
                int p = atomicAdd(&cnt, 1);
                selIdx[p] = c0;
                selVal[p] = hvA;
            }
            if (selB) {
                int p = atomicAdd(&cnt, 1);
                selIdx[p] = c1;
                selVal[p] = hvB;
            }
        }
        __syncthreads();

        // ---------- sparse decoder: x_ext = h_sel @ dec_w + dec_b ----------
        if (tid < 160) {
            float a2 = decb[tid];
            for (int k = 0; k < 64; ++k)
                a2 += selVal[k] * decw[selIdx[k] * 160 + tid];
            xext[tid] = a2;
        }
        __syncthreads();

        // ---------- y_ele gather, loss, residual updates ----------
        float ye = 0.f, yrv = 0.f, lp = 0.f;
        if (tid < 80) {
            ye  = xext[80 - hind + tid];
            yrv = yr[tid];
            float d = ye - yrv;
            lp = (yy[tid] == 0.0f) ? 0.f : d * d;
        }
        {
            float ls = lp;
            #pragma unroll
            for (int off = 32; off; off >>= 1) ls += __shfl_xor(ls, off);
            if (lane == 0) rv[wid] = ls;
            __syncthreads();
            if (tid == 0) {
                float s = 0.f;
                for (int k = 0; k < 4; ++k) s += rv[k];
                blockLoss += (double)s;
            }
        }
        float xe = 0.f;
        if (tid < 80) xe = yap[tid + 159 - theta];
        __syncthreads();
        if (tid < 80) {
            yr[tid] = yrv - ye;
            xr[tid] -= xe;
        }
    }

    if (tid == 0) atomicAdd(lossSum, blockLoss);
}

__global__ void finish_kernel(const double* __restrict__ lossSum,
                              const int* __restrict__ nz,
                              float* __restrict__ out)
{
    int n = *nz;
    if (n < 1) n = 1;
    out[0] = (float)(*lossSum / (8.0 * (double)n));
}

extern "C" void kernel_launch(void* const* d_in, const int* in_sizes, int n_in,
                              void* d_out, int out_size, void* d_ws, size_t ws_size,
                              hipStream_t stream) {
    (void)in_sizes; (void)n_in; (void)out_size; (void)ws_size;
    const float* x    = (const float*)d_in[0];
    const float* y    = (const float*)d_in[1];
    const float* encw = (const float*)d_in[2];
    const float* encb = (const float*)d_in[3];
    const float* decw = (const float*)d_in[4];
    const float* decb = (const float*)d_in[5];

    unsigned short* whi = (unsigned short*)d_ws;                       // 512*160 bf16
    unsigned short* wlo = (unsigned short*)((char*)d_ws + 163840);     // 512*160 bf16
    double* lossSum = (double*)((char*)d_ws + 327680);
    int*    nz      = (int*)((char*)d_ws + 327688);

    hipMemsetAsync((char*)d_ws + 327680, 0, 16, stream);
    prep_kernel<<<320, 256, 0, stream>>>(encw, whi, wlo);
    mp_kernel<<<2048, 256, 0, stream>>>(x, y, encw, encb, decw, decb,
                                        whi, wlo, lossSum, nz);
    finish_kernel<<<1, 1, 0, stream>>>(lossSum, nz, (float*)d_out);
}